// Round 12
// baseline (157.424 us; speedup 1.0000x reference)
//
#include <hip/hip_runtime.h>
#include <hip/hip_bf16.h>

#define EPS 1e-5f
#define LOG2E 1.44269504088896f
#define LN2   0.69314718055995f

typedef float v2f __attribute__((ext_vector_type(2)));

// ---- workspace layout (float offsets) ----
#define OFF_U    589824     // 128*64*256  = 2097152
#define OFF_V    2686976    // 2097152
#define OFF_PART 4784128    // 2048*256 = 524288 floats
// R2: NO cross-block fence/atomic handoff. R3: wave count > LDS saving.
// R4-R10: k_pair pinned ~41-46us across 7 structural variants; ablation
// says reduce-chain ~31us but phase-split fixes only shave ~3.
// R8/R9/R10 budget arithmetic: ~5-10us per dispatch boundary => cut
// dispatch count. R1 lesson: embed redundancy cost is LINEAR (x8 = 48us)
// => fuse K1+K2 at x2 redundancy only (256 blocks, 2/b).
// R11: container failed twice (infra, as R7) — identical resubmission.

__device__ __forceinline__ float elu(float z) {
    return z > 0.f ? z : __expf(z) - 1.f;
}

__device__ __forceinline__ v2f vmin0(v2f a) {
#if __has_builtin(__builtin_elementwise_min)
    return __builtin_elementwise_min(a, (v2f){0.f, 0.f});
#else
    return (v2f){fminf(a.x, 0.f), fminf(a.y, 0.f)};
#endif
}
__device__ __forceinline__ v2f vmax0(v2f a) {
#if __has_builtin(__builtin_elementwise_max)
    return __builtin_elementwise_max(a, (v2f){0.f, 0.f});
#else
    return (v2f){fmaxf(a.x, 0.f), fmaxf(a.y, 0.f)};
#endif
}

template <int CTRL>
__device__ __forceinline__ float ror_add(float x) {
    int xi = __builtin_bit_cast(int, x);
    int yi = __builtin_amdgcn_update_dpp(xi, xi, CTRL, 0xF, 0xF, false);
    return x + __builtin_bit_cast(float, yi);
}
__device__ __forceinline__ float row16_sum(float x) {
    x = ror_add<0x128>(x);   // row_ror:8
    x = ror_add<0x124>(x);   // row_ror:4
    x = ror_add<0x122>(x);   // row_ror:2
    x = ror_add<0x121>(x);   // row_ror:1
    return x;
}

// K12 v2: K1+K2 fused at x2 embed redundancy. 256 blocks = 2 per b;
// each block computes the FULL per-b embed + LN stats (x2 redundant),
// scatters its 32-row half (LN applied) into LDS, then runs the U/V GEMM
// for those 32 rows (Wg hoisted per-e across 4 q-slices). Removes: K1
// dispatch + boundary + abar HBM round-trip.
__global__ __launch_bounds__(256) void k_embed_uv(
    const float* __restrict__ xa, const float* __restrict__ xb,
    const float* __restrict__ Wa, const float* __restrict__ ba,
    const float* __restrict__ Wb, const float* __restrict__ bb,
    const float* __restrict__ g0, const float* __restrict__ b0,
    const float* __restrict__ Wg, const float* __restrict__ bg,
    float* __restrict__ U, float* __restrict__ V) {
    int blk = blockIdx.x;            // 256
    int b    = blk >> 1;
    int n0   = (blk & 1) * 32;       // this block's 32-row half
    int tid  = threadIdx.x;

    __shared__ float S[3888];        // staging (as K1)
    __shared__ float sa[72 * 32];    // [e][n-n0], 9 KB
    __shared__ float r1[4], r2[4];
    float* s_xa = S;                 // 736  = 32*23
    float* s_xb = S + 736;           // 416  = 32*13
    float* s_Wa = S + 1152;          // 1656 = 23*72
    float* s_Wb = S + 2808;          // 936  = 13*72
    float* s_ba = S + 3744;          // 72
    float* s_bb = S + 3816;          // 72
    for (int k = tid; k < 736;  k += 256) s_xa[k] = xa[b * 736 + k];
    for (int k = tid; k < 416;  k += 256) s_xb[k] = xb[b * 416 + k];
    for (int k = tid; k < 1656; k += 256) s_Wa[k] = Wa[k];
    for (int k = tid; k < 936;  k += 256) s_Wb[k] = Wb[k];
    if (tid < 72) { s_ba[tid] = ba[tid]; s_bb[tid] = bb[tid]; }
    __syncthreads();

    // ---- full-b embed + LN0 statistics (K1 v2 body) ----
    float vals[18];
    float s1 = 0.f, s2 = 0.f;
    #pragma unroll
    for (int m = 0; m < 18; ++m) {
        int k = tid + 256 * m;
        int e = k % 72;
        int n = k / 72;
        float acc;
        if (n < 32) {
            acc = s_ba[e];
            const float* x = s_xa + n * 23;
            #pragma unroll
            for (int d = 0; d < 23; ++d) acc = fmaf(x[d], s_Wa[d * 72 + e], acc);
        } else {
            acc = s_bb[e];
            const float* x = s_xb + (n - 32) * 13;
            #pragma unroll
            for (int d = 0; d < 13; ++d) acc = fmaf(x[d], s_Wb[d * 72 + e], acc);
        }
        vals[m] = acc;
        s1 += acc;
        s2 = fmaf(acc, acc, s2);
    }
    #pragma unroll
    for (int off = 32; off >= 1; off >>= 1) {
        s1 += __shfl_xor(s1, off, 64);
        s2 += __shfl_xor(s2, off, 64);
    }
    int w = tid >> 6;
    if ((tid & 63) == 0) { r1[w] = s1; r2[w] = s2; }
    __syncthreads();
    float t1 = r1[0] + r1[1] + r1[2] + r1[3];
    float t2 = r2[0] + r2[1] + r2[2] + r2[3];
    float mean = t1 * (1.f / 4608.f);
    float var  = fmaf(-mean, mean, t2 * (1.f / 4608.f));
    float rsq  = rsqrtf(var + EPS);

    // ---- scatter this block's 32 LN'd rows into sa[e][n-n0] ----
    #pragma unroll
    for (int m = 0; m < 18; ++m) {
        int k = tid + 256 * m;
        int dn = k / 72 - n0;
        if ((unsigned)dn < 32u) {
            int e = k % 72;
            sa[e * 32 + dn] = fmaf((vals[m] - mean) * rsq, g0[k], b0[k]);
        }
    }
    __syncthreads();

    // ---- U/V GEMM for the 32 rows: Wg hoisted per-e across 4 q-slices ----
    int h = tid;
    float u[4][8], v[4][8];
    #pragma unroll
    for (int q = 0; q < 4; ++q)
        #pragma unroll
        for (int n = 0; n < 8; ++n) { u[q][n] = 0.f; v[q][n] = 0.f; }
    #pragma unroll 2
    for (int e = 0; e < 72; ++e) {
        float wu = Wg[e * 256 + h];
        float wv = Wg[(72 + e) * 256 + h];
        const float4* sp = (const float4*)&sa[e * 32];
        #pragma unroll
        for (int q = 0; q < 4; ++q) {
            float4 sA = sp[2 * q];
            float4 sB = sp[2 * q + 1];
            u[q][0] = fmaf(sA.x, wu, u[q][0]); v[q][0] = fmaf(sA.x, wv, v[q][0]);
            u[q][1] = fmaf(sA.y, wu, u[q][1]); v[q][1] = fmaf(sA.y, wv, v[q][1]);
            u[q][2] = fmaf(sA.z, wu, u[q][2]); v[q][2] = fmaf(sA.z, wv, v[q][2]);
            u[q][3] = fmaf(sA.w, wu, u[q][3]); v[q][3] = fmaf(sA.w, wv, v[q][3]);
            u[q][4] = fmaf(sB.x, wu, u[q][4]); v[q][4] = fmaf(sB.x, wv, v[q][4]);
            u[q][5] = fmaf(sB.y, wu, u[q][5]); v[q][5] = fmaf(sB.y, wv, v[q][5]);
            u[q][6] = fmaf(sB.z, wu, u[q][6]); v[q][6] = fmaf(sB.z, wv, v[q][6]);
            u[q][7] = fmaf(sB.w, wu, u[q][7]); v[q][7] = fmaf(sB.w, wv, v[q][7]);
        }
    }
    float bgh = bg[h];
    #pragma unroll
    for (int q = 0; q < 4; ++q) {
        int base = (b * 64 + n0 + q * 8) * 256 + h;
        #pragma unroll
        for (int n = 0; n < 8; ++n) {
            U[base + n * 256] = (u[q][n] + bgh) * LOG2E;   // bg + log2e folded
            V[base + n * 256] = v[q][n] * LOG2E;
        }
    }
}

// K3 v20 (FROZEN, R10): phase-split + full jq unroll, DPP row reduce,
// log2e fold (t = fma(max(zs,0), ln2, exp2(min(zs,0)))).
__global__ __launch_bounds__(256) void k_pair(
    const float* __restrict__ U, const float* __restrict__ V,
    float* __restrict__ part) {
    int blk = (blockIdx.x & 7) * 256 + (blockIdx.x >> 3);
    int b  = blk >> 4;
    int iq = blk & 15;
    int t  = threadIdx.x;
    int j16 = t >> 4;
    int hc  = t & 15;

    __shared__ float Sc[16 * 256];

    v2f u2[4][8];
    #pragma unroll
    for (int i = 0; i < 4; ++i) {
        const float* Ur = U + (size_t)(b * 64 + iq * 4 + i) * 256;
        #pragma unroll
        for (int c = 0; c < 4; ++c) {
            float4 x = *(const float4*)&Ur[hc * 4 + 64 * c];
            u2[i][2*c]   = (v2f){x.x, x.y};
            u2[i][2*c+1] = (v2f){x.z, x.w};
        }
    }

    #pragma unroll
    for (int jq = 0; jq < 4; ++jq) {
        const float* Vrow = V + (size_t)(b * 64 + jq * 16 + j16) * 256;
        v2f v[8];
        #pragma unroll
        for (int c = 0; c < 4; ++c) {
            float4 v4 = *(const float4*)&Vrow[hc * 4 + 64 * c];
            v[2*c]   = (v2f){v4.x, v4.y};
            v[2*c+1] = (v2f){v4.z, v4.w};
        }

        v2f acc[8];
        #pragma unroll
        for (int k = 0; k < 8; ++k) acc[k] = (v2f){0.f, 0.f};
        float macc = 0.f;

        // phase 1: elementwise for all 4 i
        v2f t2[4][8];
        float s1h[4], s2h[4];
        #pragma unroll
        for (int i = 0; i < 4; ++i) {
            v2f s1v = (v2f){0.f, 0.f};
            v2f s2v = (v2f){0.f, 0.f};
            #pragma unroll
            for (int c = 0; c < 8; ++c) {
                v2f z  = u2[i][c] + v[c];              // zs = z*log2e
                v2f mn = vmin0(z);
                v2f mx = vmax0(z);
                v2f ex;
                ex.x = __builtin_amdgcn_exp2f(mn.x);
                ex.y = __builtin_amdgcn_exp2f(mn.y);
                v2f tt = mx * (v2f){LN2, LN2} + ex;    // elu(z)+1
                t2[i][c] = tt;
                s1v += tt;
                s2v = tt * tt + s2v;
            }
            s1h[i] = s1v.x + s1v.y;
            s2h[i] = s2v.x + s2v.y;
        }
        // phase 2: 8 independent DPP reduce chains
        #pragma unroll
        for (int i = 0; i < 4; ++i) {
            s1h[i] = row16_sum(s1h[i]);
            s2h[i] = row16_sum(s2h[i]);
        }
        // phase 3: 4 independent rsqrt
        float rsq4[4];
        #pragma unroll
        for (int i = 0; i < 4; ++i) {
            float mu  = s1h[i] * (1.f / 256.f);
            float var = fmaf(-mu, mu, s2h[i] * (1.f / 256.f));
            rsq4[i] = rsqrtf(var + EPS);
            macc += mu * rsq4[i];
        }
        // phase 4: batched acc updates
        #pragma unroll
        for (int i = 0; i < 4; ++i) {
            v2f r2 = (v2f){rsq4[i], rsq4[i]};
            #pragma unroll
            for (int k = 0; k < 8; ++k) acc[k] = t2[i][k] * r2 + acc[k];
        }
        v2f m2 = (v2f){macc, macc};
        #pragma unroll
        for (int k = 0; k < 8; ++k) acc[k] -= m2;

        if (jq == 0) {
            #pragma unroll
            for (int c = 0; c < 4; ++c)
                *(float4*)&Sc[j16 * 256 + hc * 4 + 64 * c] =
                    make_float4(acc[2*c].x, acc[2*c].y, acc[2*c+1].x, acc[2*c+1].y);
        } else {
            #pragma unroll
            for (int c = 0; c < 4; ++c) {
                float* p = &Sc[j16 * 256 + hc * 4 + 64 * c];
                float4 old = *(const float4*)p;
                *(float4*)p = make_float4(old.x + acc[2*c].x, old.y + acc[2*c].y,
                                          old.z + acc[2*c+1].x, old.w + acc[2*c+1].y);
            }
        }
    }

    __syncthreads();
    float r = 0.f;
    #pragma unroll
    for (int q = 0; q < 16; ++q) r += Sc[q * 256 + t];
    part[(size_t)blk * 256 + t] = r;
}

// K4 v5 (FROZEN): part is [128][16][256].
__global__ __launch_bounds__(512) void k_out(
    const float* __restrict__ part,
    const float* __restrict__ lgg, const float* __restrict__ lgb,
    const float* __restrict__ Wf,  const float* __restrict__ bfb,
    float* __restrict__ out) {
    int b = blockIdx.x;
    int t = threadIdx.x;
    __shared__ float sh[256];
    __shared__ float ps[512];
    {
        int h = t & 255, pg = t >> 8;
        float s = 0.f;
        #pragma unroll
        for (int p = 0; p < 8; ++p)
            s += part[(size_t)(b * 16 + pg * 8 + p) * 256 + h];
        ps[t] = s;
    }
    __syncthreads();
    if (t < 256) sh[t] = fmaf(lgg[t], ps[t] + ps[t + 256], 4096.f * lgb[t]);
    __syncthreads();
    {
        int f = t & 127, hq = t >> 7;
        float acc = 0.f;
        #pragma unroll 8
        for (int h = hq * 64; h < hq * 64 + 64; ++h)
            acc = fmaf(sh[h], Wf[h * 128 + f], acc);
        ps[t] = acc;
    }
    __syncthreads();
    if (t < 128) {
        float r = ps[t] + ps[t + 128] + ps[t + 256] + ps[t + 384] + bfb[t];
        out[b * 128 + t] = r > 0.f ? r : __expf(r) - 1.f;
    }
}

extern "C" void kernel_launch(void* const* d_in, const int* in_sizes, int n_in,
                              void* d_out, int out_size, void* d_ws, size_t ws_size,
                              hipStream_t stream) {
    const float* xa  = (const float*)d_in[0];
    const float* xb  = (const float*)d_in[1];
    const float* Wa  = (const float*)d_in[2];
    const float* ba  = (const float*)d_in[3];
    const float* Wb  = (const float*)d_in[4];
    const float* bb  = (const float*)d_in[5];
    const float* g0  = (const float*)d_in[6];
    const float* b0  = (const float*)d_in[7];
    const float* Wg  = (const float*)d_in[8];
    const float* bg  = (const float*)d_in[9];
    const float* lgg = (const float*)d_in[10];
    const float* lgb = (const float*)d_in[11];
    const float* Wf  = (const float*)d_in[12];
    const float* bfb = (const float*)d_in[13];
    float* out = (float*)d_out;

    float* ws   = (float*)d_ws;
    float* U    = ws + OFF_U;
    float* V    = ws + OFF_V;
    float* part = ws + OFF_PART;

    k_embed_uv<<<256, 256, 0, stream>>>(xa, xb, Wa, ba, Wb, bb, g0, b0,
                                        Wg, bg, U, V);
    k_pair<<<2048, 256, 0, stream>>>(U, V, part);
    k_out<<<128, 512, 0, stream>>>(part, lgg, lgb, Wf, bfb, out);
}

// Round 13
// 148.418 us; speedup vs baseline: 1.0607x; 1.0607x over previous
//
#include <hip/hip_runtime.h>
#include <hip/hip_bf16.h>

#define EPS 1e-5f
#define LOG2E 1.44269504088896f
#define LN2   0.69314718055995f

typedef float v2f __attribute__((ext_vector_type(2)));

// ---- workspace layout (float offsets) ----
#define OFF_ABAR 0          // 128*64*72   = 589824 floats
#define OFF_U    589824     // 128*64*256  = 2097152
#define OFF_V    2686976    // 2097152
#define OFF_PART 4784128    // 2048*256 = 524288 floats
// Session ledger:
// R2: NO cross-block fence/atomic handoff (per-block device fence = L2
//     writeback, 423us). R3: wave count > LDS-traffic saving.
// R4-R10: k_pair pinned 41-46us across 8 variants (occupancy 18-42%,
//     instr count +-30%, shuffle->DPP, LDS->reg U). Ablation: elementwise
//     ~6 + exp ~7 + reduce-chain ~31; phase-split recovered ~3.
// R1/R2/R12: all three K-fusion mechanisms null or negative => dispatch
//     boundaries are NOT recoverable at this op's scale.
// R13: bank the best stable config (R10 assembly). Next lever (untaken:
//     precision-gated) = MFMA bf16 t@t^T for s2.

__device__ __forceinline__ float elu(float z) {
    return z > 0.f ? z : __expf(z) - 1.f;
}

__device__ __forceinline__ v2f vmin0(v2f a) {
#if __has_builtin(__builtin_elementwise_min)
    return __builtin_elementwise_min(a, (v2f){0.f, 0.f});
#else
    return (v2f){fminf(a.x, 0.f), fminf(a.y, 0.f)};
#endif
}
__device__ __forceinline__ v2f vmax0(v2f a) {
#if __has_builtin(__builtin_elementwise_max)
    return __builtin_elementwise_max(a, (v2f){0.f, 0.f});
#else
    return (v2f){fmaxf(a.x, 0.f), fmaxf(a.y, 0.f)};
#endif
}

template <int CTRL>
__device__ __forceinline__ float ror_add(float x) {
    int xi = __builtin_bit_cast(int, x);
    int yi = __builtin_amdgcn_update_dpp(xi, xi, CTRL, 0xF, 0xF, false);
    return x + __builtin_bit_cast(float, yi);
}
__device__ __forceinline__ float row16_sum(float x) {
    x = ror_add<0x128>(x);   // row_ror:8
    x = ror_add<0x124>(x);   // row_ror:4
    x = ror_add<0x122>(x);   // row_ror:2
    x = ror_add<0x121>(x);   // row_ror:1
    return x;
}

// K1 v2 (FROZEN): fused split-embedding + LayerNorm.
__global__ __launch_bounds__(256) void k_embed_ln0(
    const float* __restrict__ xa, const float* __restrict__ xb,
    const float* __restrict__ Wa, const float* __restrict__ ba,
    const float* __restrict__ Wb, const float* __restrict__ bb,
    const float* __restrict__ g0, const float* __restrict__ b0,
    float* __restrict__ abar) {
    int b = blockIdx.x;
    int tid = threadIdx.x;
    __shared__ float S[3888];
    float* s_xa = S;
    float* s_xb = S + 736;
    float* s_Wa = S + 1152;
    float* s_Wb = S + 2808;
    float* s_ba = S + 3744;
    float* s_bb = S + 3816;
    for (int k = tid; k < 736;  k += 256) s_xa[k] = xa[b * 736 + k];
    for (int k = tid; k < 416;  k += 256) s_xb[k] = xb[b * 416 + k];
    for (int k = tid; k < 1656; k += 256) s_Wa[k] = Wa[k];
    for (int k = tid; k < 936;  k += 256) s_Wb[k] = Wb[k];
    if (tid < 72) { s_ba[tid] = ba[tid]; s_bb[tid] = bb[tid]; }
    __syncthreads();

    float vals[18];
    float s1 = 0.f, s2 = 0.f;
    #pragma unroll
    for (int m = 0; m < 18; ++m) {
        int k = tid + 256 * m;
        int e = k % 72;
        int n = k / 72;
        float acc;
        if (n < 32) {
            acc = s_ba[e];
            const float* x = s_xa + n * 23;
            #pragma unroll
            for (int d = 0; d < 23; ++d) acc = fmaf(x[d], s_Wa[d * 72 + e], acc);
        } else {
            acc = s_bb[e];
            const float* x = s_xb + (n - 32) * 13;
            #pragma unroll
            for (int d = 0; d < 13; ++d) acc = fmaf(x[d], s_Wb[d * 72 + e], acc);
        }
        vals[m] = acc;
        s1 += acc;
        s2 = fmaf(acc, acc, s2);
    }
    #pragma unroll
    for (int off = 32; off >= 1; off >>= 1) {
        s1 += __shfl_xor(s1, off, 64);
        s2 += __shfl_xor(s2, off, 64);
    }
    __shared__ float r1[4], r2[4];
    int w = tid >> 6;
    if ((tid & 63) == 0) { r1[w] = s1; r2[w] = s2; }
    __syncthreads();
    float t1 = r1[0] + r1[1] + r1[2] + r1[3];
    float t2 = r2[0] + r2[1] + r2[2] + r2[3];
    float mean = t1 * (1.f / 4608.f);
    float var  = fmaf(-mean, mean, t2 * (1.f / 4608.f));
    float rsq  = rsqrtf(var + EPS);
    float* ab = abar + b * 4608;
    #pragma unroll
    for (int m = 0; m < 18; ++m) {
        int k = tid + 256 * m;
        ab[k] = fmaf((vals[m] - mean) * rsq, g0[k], b0[k]);
    }
}

// K2 v4 (FROZEN): U/V GEMM, 1024 blocks, unroll-6 e-loop, log2e fold.
__global__ __launch_bounds__(256) void k_uv(
    const float* __restrict__ abar, const float* __restrict__ Wg,
    const float* __restrict__ bg,
    float* __restrict__ U, float* __restrict__ V) {
    int blk = blockIdx.x;
    int b = blk >> 3;
    int q = blk & 7;
    int h = threadIdx.x;
    __shared__ float sa[72 * 8];
    const float* src = abar + (b * 64 + q * 8) * 72;
    for (int k = threadIdx.x; k < 72 * 8; k += 256) {
        int e = k >> 3, n = k & 7;
        sa[k] = src[n * 72 + e];
    }
    __syncthreads();
    float u[8], v[8];
    #pragma unroll
    for (int n = 0; n < 8; ++n) { u[n] = 0.f; v[n] = 0.f; }
    #pragma unroll 6
    for (int e = 0; e < 72; ++e) {
        float wu = Wg[e * 256 + h];
        float wv = Wg[(72 + e) * 256 + h];
        const float4* sp = (const float4*)&sa[e * 8];
        #pragma unroll
        for (int n4 = 0; n4 < 2; ++n4) {
            float4 s4 = sp[n4];
            u[n4*4+0] = fmaf(s4.x, wu, u[n4*4+0]); v[n4*4+0] = fmaf(s4.x, wv, v[n4*4+0]);
            u[n4*4+1] = fmaf(s4.y, wu, u[n4*4+1]); v[n4*4+1] = fmaf(s4.y, wv, v[n4*4+1]);
            u[n4*4+2] = fmaf(s4.z, wu, u[n4*4+2]); v[n4*4+2] = fmaf(s4.z, wv, v[n4*4+2]);
            u[n4*4+3] = fmaf(s4.w, wu, u[n4*4+3]); v[n4*4+3] = fmaf(s4.w, wv, v[n4*4+3]);
        }
    }
    float bgh = bg[h];
    int base = (b * 64 + q * 8) * 256 + h;
    #pragma unroll
    for (int n = 0; n < 8; ++n) {
        U[base + n * 256] = (u[n] + bgh) * LOG2E;   // bg + log2e folded
        V[base + n * 256] = v[n] * LOG2E;
    }
}

// K3 v20 (FROZEN, best measured): phase-split + full jq unroll, DPP row
// reduce, log2e fold (t = fma(max(zs,0), ln2, exp2(min(zs,0)))).
__global__ __launch_bounds__(256) void k_pair(
    const float* __restrict__ U, const float* __restrict__ V,
    float* __restrict__ part) {
    int blk = (blockIdx.x & 7) * 256 + (blockIdx.x >> 3);
    int b  = blk >> 4;
    int iq = blk & 15;
    int t  = threadIdx.x;
    int j16 = t >> 4;
    int hc  = t & 15;

    __shared__ float Sc[16 * 256];

    v2f u2[4][8];
    #pragma unroll
    for (int i = 0; i < 4; ++i) {
        const float* Ur = U + (size_t)(b * 64 + iq * 4 + i) * 256;
        #pragma unroll
        for (int c = 0; c < 4; ++c) {
            float4 x = *(const float4*)&Ur[hc * 4 + 64 * c];
            u2[i][2*c]   = (v2f){x.x, x.y};
            u2[i][2*c+1] = (v2f){x.z, x.w};
        }
    }

    #pragma unroll
    for (int jq = 0; jq < 4; ++jq) {
        const float* Vrow = V + (size_t)(b * 64 + jq * 16 + j16) * 256;
        v2f v[8];
        #pragma unroll
        for (int c = 0; c < 4; ++c) {
            float4 v4 = *(const float4*)&Vrow[hc * 4 + 64 * c];
            v[2*c]   = (v2f){v4.x, v4.y};
            v[2*c+1] = (v2f){v4.z, v4.w};
        }

        v2f acc[8];
        #pragma unroll
        for (int k = 0; k < 8; ++k) acc[k] = (v2f){0.f, 0.f};
        float macc = 0.f;

        // phase 1: elementwise for all 4 i
        v2f t2[4][8];
        float s1h[4], s2h[4];
        #pragma unroll
        for (int i = 0; i < 4; ++i) {
            v2f s1v = (v2f){0.f, 0.f};
            v2f s2v = (v2f){0.f, 0.f};
            #pragma unroll
            for (int c = 0; c < 8; ++c) {
                v2f z  = u2[i][c] + v[c];              // zs = z*log2e
                v2f mn = vmin0(z);
                v2f mx = vmax0(z);
                v2f ex;
                ex.x = __builtin_amdgcn_exp2f(mn.x);
                ex.y = __builtin_amdgcn_exp2f(mn.y);
                v2f tt = mx * (v2f){LN2, LN2} + ex;    // elu(z)+1
                t2[i][c] = tt;
                s1v += tt;
                s2v = tt * tt + s2v;
            }
            s1h[i] = s1v.x + s1v.y;
            s2h[i] = s2v.x + s2v.y;
        }
        // phase 2: 8 independent DPP reduce chains
        #pragma unroll
        for (int i = 0; i < 4; ++i) {
            s1h[i] = row16_sum(s1h[i]);
            s2h[i] = row16_sum(s2h[i]);
        }
        // phase 3: 4 independent rsqrt
        float rsq4[4];
        #pragma unroll
        for (int i = 0; i < 4; ++i) {
            float mu  = s1h[i] * (1.f / 256.f);
            float var = fmaf(-mu, mu, s2h[i] * (1.f / 256.f));
            rsq4[i] = rsqrtf(var + EPS);
            macc += mu * rsq4[i];
        }
        // phase 4: batched acc updates
        #pragma unroll
        for (int i = 0; i < 4; ++i) {
            v2f r2 = (v2f){rsq4[i], rsq4[i]};
            #pragma unroll
            for (int k = 0; k < 8; ++k) acc[k] = t2[i][k] * r2 + acc[k];
        }
        v2f m2 = (v2f){macc, macc};
        #pragma unroll
        for (int k = 0; k < 8; ++k) acc[k] -= m2;

        if (jq == 0) {
            #pragma unroll
            for (int c = 0; c < 4; ++c)
                *(float4*)&Sc[j16 * 256 + hc * 4 + 64 * c] =
                    make_float4(acc[2*c].x, acc[2*c].y, acc[2*c+1].x, acc[2*c+1].y);
        } else {
            #pragma unroll
            for (int c = 0; c < 4; ++c) {
                float* p = &Sc[j16 * 256 + hc * 4 + 64 * c];
                float4 old = *(const float4*)p;
                *(float4*)p = make_float4(old.x + acc[2*c].x, old.y + acc[2*c].y,
                                          old.z + acc[2*c+1].x, old.w + acc[2*c+1].y);
            }
        }
    }

    __syncthreads();
    float r = 0.f;
    #pragma unroll
    for (int q = 0; q < 16; ++q) r += Sc[q * 256 + t];
    part[(size_t)blk * 256 + t] = r;
}

// K4 v5 (FROZEN): part is [128][16][256].
__global__ __launch_bounds__(512) void k_out(
    const float* __restrict__ part,
    const float* __restrict__ lgg, const float* __restrict__ lgb,
    const float* __restrict__ Wf,  const float* __restrict__ bfb,
    float* __restrict__ out) {
    int b = blockIdx.x;
    int t = threadIdx.x;
    __shared__ float sh[256];
    __shared__ float ps[512];
    {
        int h = t & 255, pg = t >> 8;
        float s = 0.f;
        #pragma unroll
        for (int p = 0; p < 8; ++p)
            s += part[(size_t)(b * 16 + pg * 8 + p) * 256 + h];
        ps[t] = s;
    }
    __syncthreads();
    if (t < 256) sh[t] = fmaf(lgg[t], ps[t] + ps[t + 256], 4096.f * lgb[t]);
    __syncthreads();
    {
        int f = t & 127, hq = t >> 7;
        float acc = 0.f;
        #pragma unroll 8
        for (int h = hq * 64; h < hq * 64 + 64; ++h)
            acc = fmaf(sh[h], Wf[h * 128 + f], acc);
        ps[t] = acc;
    }
    __syncthreads();
    if (t < 128) {
        float r = ps[t] + ps[t + 128] + ps[t + 256] + ps[t + 384] + bfb[t];
        out[b * 128 + t] = r > 0.f ? r : __expf(r) - 1.f;
    }
}

extern "C" void kernel_launch(void* const* d_in, const int* in_sizes, int n_in,
                              void* d_out, int out_size, void* d_ws, size_t ws_size,
                              hipStream_t stream) {
    const float* xa  = (const float*)d_in[0];
    const float* xb  = (const float*)d_in[1];
    const float* Wa  = (const float*)d_in[2];
    const float* ba  = (const float*)d_in[3];
    const float* Wb  = (const float*)d_in[4];
    const float* bb  = (const float*)d_in[5];
    const float* g0  = (const float*)d_in[6];
    const float* b0  = (const float*)d_in[7];
    const float* Wg  = (const float*)d_in[8];
    const float* bg  = (const float*)d_in[9];
    const float* lgg = (const float*)d_in[10];
    const float* lgb = (const float*)d_in[11];
    const float* Wf  = (const float*)d_in[12];
    const float* bfb = (const float*)d_in[13];
    float* out = (float*)d_out;

    float* ws   = (float*)d_ws;
    float* abar = ws + OFF_ABAR;
    float* U    = ws + OFF_U;
    float* V    = ws + OFF_V;
    float* part = ws + OFF_PART;

    k_embed_ln0<<<128, 256, 0, stream>>>(xa, xb, Wa, ba, Wb, bb, g0, b0, abar);
    k_uv<<<1024, 256, 0, stream>>>(abar, Wg, bg, U, V);
    k_pair<<<2048, 256, 0, stream>>>(U, V, part);
    k_out<<<128, 512, 0, stream>>>(part, lgg, lgb, Wf, bfb, out);
}